// Round 4
// baseline (435.340 us; speedup 1.0000x reference)
//
#include <hip/hip_runtime.h>
#include <hip/hip_bf16.h>
#include <stdint.h>

#define NB 64
#define NT 1024
#define CIN 8
#define NE 256
#define NO 63
#define TPAD 16
#define TROWS (NT + 2*TPAD)   // 1056
#define LCH 128               // LIF chunk length
#define LWU 48                // LIF warm-up steps (2^-48 decay << fp32 ulp)

using bf16x8 = __attribute__((ext_vector_type(8))) short;
using f32x4  = __attribute__((ext_vector_type(4))) float;
using i32x4  = __attribute__((ext_vector_type(4))) int;

// ---- weight split + fragment reorder: convs_w [3][E][E][3] fp32 ->
//      Wfr [l][k][s][e4(16)][cph(8)][lane(64)*8]  bf16, per-lane A-frag order ----
__global__ void prep_w(const float* __restrict__ cw, __hip_bfloat16* __restrict__ wfr) {
    int F = blockIdx.x * 256 + threadIdx.x;          // 576 blocks -> 147456 lanes
    int lane = F & 63;
    int x = F >> 6;
    int cph = x & 7;  x >>= 3;
    int e4  = x & 15; x >>= 4;
    int s   = x & 1;  x >>= 1;
    int k   = x % 3;
    int l   = x / 3;
    int e = e4*16 + (lane & 15);
    int cb = cph*32 + (lane >> 4)*8;
    __hip_bfloat16 outv[8];
    #pragma unroll
    for (int j = 0; j < 8; ++j) {
        float w = cw[((size_t)(l*256 + e)*256 + (cb + j))*3 + k];
        __hip_bfloat16 hi = __float2bfloat16(w);
        if (s == 0) outv[j] = hi;
        else        outv[j] = __float2bfloat16(w - __bfloat162float(hi));
    }
    *(uint4*)(wfr + (size_t)F*8) = *(uint4*)outv;
}

// ---------------- conv0: x [B][T][CIN] -> y [B][T][E] fp32 (+bias) + block stats ----------
__global__ void conv0_kern(const float* __restrict__ x, const float* __restrict__ w0,
                           const float* __restrict__ b0, float* __restrict__ y,
                           float* __restrict__ part) {
    int b = blockIdx.y, tc = blockIdx.x;            // tc: 8 chunks of 128 t
    int e = threadIdx.x;
    int t0 = tc * 128;
    __shared__ float xs[1040];                      // 130 t-rows x 8 c
    for (int i = threadIdx.x; i < 1040; i += 256) {
        int t = t0 - 1 + (i >> 3); int c = i & 7;
        xs[i] = (t >= 0 && t < NT) ? x[((size_t)b*NT + t)*CIN + c] : 0.0f;
    }
    __syncthreads();
    float w[24];
    #pragma unroll
    for (int j = 0; j < 24; ++j) w[j] = w0[e*24 + j];   // [e][c][k]
    float bias = b0[e];
    float s = 0.0f, qq = 0.0f;
    for (int dt = 0; dt < 128; ++dt) {
        float acc = bias;
        #pragma unroll
        for (int c = 0; c < 8; ++c)
            #pragma unroll
            for (int k = 0; k < 3; ++k)
                acc += xs[(dt + k)*8 + c] * w[c*3 + k];
        y[((size_t)b*NT + t0 + dt)*NE + e] = acc;
        s += acc; qq += acc*acc;
    }
    int p = b*8 + tc;
    part[(size_t)p*512 + e]       = s;
    part[(size_t)p*512 + 256 + e] = qq;
}

// ---------------- stats final: reduce np partials per e, wave-parallel ----------------
__global__ void stats_final(const float* __restrict__ part, const float* __restrict__ gamma,
                            const float* __restrict__ beta, float4* __restrict__ lifp, int np) {
    int e = blockIdx.x; int lane = threadIdx.x;
    double s = 0.0, q = 0.0;
    for (int p = lane; p < np; p += 64) {
        s += (double)part[(size_t)p*512 + e];
        q += (double)part[(size_t)p*512 + 256 + e];
    }
    #pragma unroll
    for (int off = 1; off < 64; off <<= 1) {
        s += __shfl_xor(s, off, 64);
        q += __shfl_xor(q, off, 64);
    }
    if (lane == 0) {
        const double N = 65536.0;
        double mean = s / N;
        double var  = q / N - mean*mean;
        float rs = (float)(1.0 / sqrt(var + 1e-5));
        float4 o; o.x = (float)mean; o.y = rs * gamma[e]; o.z = beta[e]; o.w = 0.0f;
        lifp[e] = o;
    }
}

// ---------------- BN apply + chunked LIF scan with warm-up ----------------
__global__ void lif_kern(const float* __restrict__ y, const float4* __restrict__ lifp,
                         __hip_bfloat16* __restrict__ S) {
    int c = blockIdx.x, b = blockIdx.y;
    int e = threadIdx.x;
    float4 pr = lifp[e];
    float mu = pr.x, rsg = pr.y, bet = pr.z;
    const __hip_bfloat16 z   = __float2bfloat16(0.0f);
    const __hip_bfloat16 one = __float2bfloat16(1.0f);
    if (c == 0) {       // zero top halo
        for (int r = 0; r < TPAD; ++r) S[((size_t)b*TROWS + r)*NE + e] = z;
    }
    if (c == 7) {       // zero bottom halo
        for (int r = 0; r < TPAD; ++r) S[((size_t)b*TROWS + TPAD + NT + r)*NE + e] = z;
    }
    int t0 = c * LCH;
    int tw = t0 - LWU; if (tw < 0) tw = 0;
    const float* yb = y + (size_t)b*NT*NE + e;
    __hip_bfloat16* sb = S + ((size_t)b*TROWS + TPAD)*NE + e;
    float v = 0.0f;
    #pragma unroll 4
    for (int t = tw; t < t0; ++t) {                 // warm-up, no writes
        float xx = yb[(size_t)t*NE];
        float yn = (xx - mu)*rsg + bet;
        float d  = __fsub_rn(yn, v);
        v = __fadd_rn(v, __fmul_rn(d, 0.5f));
        v = (v >= 1.0f) ? 0.0f : v;
    }
    #pragma unroll 4
    for (int t = t0; t < t0 + LCH; ++t) {
        float xx = yb[(size_t)t*NE];
        float yn = (xx - mu)*rsg + bet;
        float d  = __fsub_rn(yn, v);
        v = __fadd_rn(v, __fmul_rn(d, 0.5f));       // v + (x - v)/TAU, TAU=2
        bool sp = (v >= 1.0f);
        sb[(size_t)t*NE] = sp ? one : z;
        v = sp ? 0.0f : v;
    }
}

// ---- DPP helpers: shift within 16-lane rows ----
__device__ __forceinline__ int dpp_shl1(int v)  { return __builtin_amdgcn_update_dpp(0, v, 0x101, 0xF, 0xF, true); }
__device__ __forceinline__ int dpp_shl2(int v)  { return __builtin_amdgcn_update_dpp(0, v, 0x102, 0xF, 0xF, true); }
__device__ __forceinline__ int dpp_shr15(int v) { return __builtin_amdgcn_update_dpp(0, v, 0x11F, 0xF, 0xF, true); }
__device__ __forceinline__ int dpp_shr14(int v) { return __builtin_amdgcn_update_dpp(0, v, 0x11E, 0xF, 0xF, true); }

// ---- main conv v3: A stationary per ph (regs), B staged once, kk taps via DPP ----
// grid (4tt, 2et, 64b); block 256 thr = 4 waves; wave w: e = et*128+w*32 (f=2), t = tt*256 (g=16)
__global__ __launch_bounds__(256, 2) void conv_mfma(
    const __hip_bfloat16* __restrict__ Sp,   // [B][TROWS][E] padded spikes
    const __hip_bfloat16* __restrict__ Wfr,  // [k][s][e4][cph][512] frag-ordered, this layer
    const float* __restrict__ bias,
    float* __restrict__ y,                   // [B][T][E]
    float* __restrict__ part)
{
    __shared__ short Bbuf[272*32];           // 272 rows x 32 c (64 B/row, swizzled) = 17408 B
    const int tid  = threadIdx.x;
    const int wv   = tid >> 6, lane = tid & 63;
    const int n16  = lane & 15, q = lane >> 4;
    const int tt = blockIdx.x, et = blockIdx.y, b = blockIdx.z;
    const int t0 = tt * 256;
    const bool sel15 = (n16 == 15);
    const bool sel14 = (n16 >= 14);

    f32x4 acc[2][16] = {};

    const __hip_bfloat16* Sbase = Sp + ((size_t)b*TROWS + (TPAD - 1 + t0)) * NE;

    // stage regs for ph 0
    uint4 st[5];
    #pragma unroll
    for (int i = 0; i < 5; ++i) {
        int idx = tid + i*256;
        if (idx < 258*4) {
            int r = idx >> 2, sg = idx & 3;
            st[i] = *(const uint4*)(Sbase + (size_t)r*NE + sg*8);
        }
    }

    for (int ph = 0; ph < 8; ++ph) {
        if (ph) __syncthreads();             // readers of previous ph done
        #pragma unroll
        for (int i = 0; i < 5; ++i) {
            int idx = tid + i*256;
            if (idx < 258*4) {
                int r = idx >> 2, sg = idx & 3;
                int sgs = sg ^ ((r >> 1) & 3);
                *(uint4*)((char*)Bbuf + r*64 + sgs*16) = st[i];
            }
        }
        __syncthreads();
        if (ph < 7) {                        // prefetch next ph's stage
            const int c1 = (ph + 1) * 32;
            #pragma unroll
            for (int i = 0; i < 5; ++i) {
                int idx = tid + i*256;
                if (idx < 258*4) {
                    int r = idx >> 2, sg = idx & 3;
                    st[i] = *(const uint4*)(Sbase + (size_t)r*NE + c1 + sg*8);
                }
            }
        }
        // A-frags for this ph: 6 (k,s) x 2 f, stationary in regs
        bf16x8 afr[6][2];
        #pragma unroll
        for (int ks = 0; ks < 6; ++ks)
            #pragma unroll
            for (int f = 0; f < 2; ++f) {
                int e4 = et*8 + wv*2 + f;
                afr[ks][f] = *(const bf16x8*)(Wfr + (((size_t)(ks*16 + e4)*8 + ph) << 9) + lane*8);
            }
        // B frag ring + MFMA
        i32x4 ring[4];
        #pragma unroll
        for (int g = 0; g < 2; ++g) {
            int row = g*16 + n16;
            int sgs = q ^ ((row >> 1) & 3);
            ring[g] = *(const i32x4*)((const char*)Bbuf + row*64 + sgs*16);
        }
        #pragma unroll
        for (int g = 0; g < 16; ++g) {
            if (g + 2 <= 16) {
                int row = (g+2)*16 + n16;
                int sgs = q ^ ((row >> 1) & 3);
                ring[(g+2) & 3] = *(const i32x4*)((const char*)Bbuf + row*64 + sgs*16);
            }
            i32x4 cur = ring[g & 3], nxt = ring[(g+1) & 3];
            i32x4 k1, k2;
            #pragma unroll
            for (int j = 0; j < 4; ++j) {
                int a1 = dpp_shl1(cur[j]), b1 = dpp_shr15(nxt[j]);
                k1[j] = sel15 ? b1 : a1;
                int a2 = dpp_shl2(cur[j]), b2 = dpp_shr14(nxt[j]);
                k2[j] = sel14 ? b2 : a2;
            }
            bf16x8 b0 = __builtin_bit_cast(bf16x8, cur);
            bf16x8 bk1 = __builtin_bit_cast(bf16x8, k1);
            bf16x8 bk2 = __builtin_bit_cast(bf16x8, k2);
            #pragma unroll
            for (int f = 0; f < 2; ++f) {
                acc[f][g] = __builtin_amdgcn_mfma_f32_16x16x32_bf16(afr[0][f], b0,  acc[f][g], 0, 0, 0);
                acc[f][g] = __builtin_amdgcn_mfma_f32_16x16x32_bf16(afr[1][f], b0,  acc[f][g], 0, 0, 0);
                acc[f][g] = __builtin_amdgcn_mfma_f32_16x16x32_bf16(afr[2][f], bk1, acc[f][g], 0, 0, 0);
                acc[f][g] = __builtin_amdgcn_mfma_f32_16x16x32_bf16(afr[3][f], bk1, acc[f][g], 0, 0, 0);
                acc[f][g] = __builtin_amdgcn_mfma_f32_16x16x32_bf16(afr[4][f], bk2, acc[f][g], 0, 0, 0);
                acc[f][g] = __builtin_amdgcn_mfma_f32_16x16x32_bf16(afr[5][f], bk2, acc[f][g], 0, 0, 0);
            }
        }
    }

    // epilogue: C col=n16 (t), row=q*4+reg (e); store y + per-wave (= distinct-e) stats
    float ls[8], lq[8];
    #pragma unroll
    for (int f = 0; f < 2; ++f) {
        int e_loc = et*128 + wv*32 + f*16 + q*4;
        float4 bv = *(const float4*)(bias + e_loc);
        float s0=0,s1=0,s2=0,s3=0, q0=0,q1=0,q2=0,q3=0;
        #pragma unroll
        for (int g = 0; g < 16; ++g) {
            int t = t0 + g*16 + n16;
            f32x4 a = acc[f][g];
            float4 o;
            o.x = a[0] + bv.x; o.y = a[1] + bv.y; o.z = a[2] + bv.z; o.w = a[3] + bv.w;
            *(float4*)(y + ((size_t)b*NT + t)*NE + e_loc) = o;
            s0 += o.x; q0 += o.x*o.x;
            s1 += o.y; q1 += o.y*o.y;
            s2 += o.z; q2 += o.z*o.z;
            s3 += o.w; q3 += o.w*o.w;
        }
        ls[f*4+0]=s0; lq[f*4+0]=q0;
        ls[f*4+1]=s1; lq[f*4+1]=q1;
        ls[f*4+2]=s2; lq[f*4+2]=q2;
        ls[f*4+3]=s3; lq[f*4+3]=q3;
    }
    #pragma unroll
    for (int off = 1; off < 16; off <<= 1) {
        #pragma unroll
        for (int i = 0; i < 8; ++i) {
            ls[i] += __shfl_xor(ls[i], off, 64);
            lq[i] += __shfl_xor(lq[i], off, 64);
        }
    }
    if (n16 == 0) {
        int p = b*4 + tt;
        #pragma unroll
        for (int f = 0; f < 2; ++f)
            #pragma unroll
            for (int r = 0; r < 4; ++r) {
                int e_glob = et*128 + wv*32 + f*16 + q*4 + r;
                part[(size_t)p*512 + e_glob]       = ls[f*4+r];
                part[(size_t)p*512 + 256 + e_glob] = lq[f*4+r];
            }
    }
}

// ---------------- head: mean over T of spikes, then [B,E]@[O,E]^T + b ----------------
__global__ void head_kern(const __hip_bfloat16* __restrict__ Sp, const float* __restrict__ hw,
                          const float* __restrict__ hb, float* __restrict__ out) {
    int b = blockIdx.x;
    int tid = threadIdx.x;
    int eg = tid & 31, ts = tid >> 5;
    __shared__ float tmp[8*256];
    __shared__ float pooled[256];
    const __hip_bfloat16* sb = Sp + ((size_t)b*TROWS + TPAD)*NE + eg*8;
    float s[8] = {0,0,0,0,0,0,0,0};
    for (int r = ts; r < NT; r += 8) {
        bf16x8 vv = *(const bf16x8*)(sb + (size_t)r*NE);
        #pragma unroll
        for (int j = 0; j < 8; ++j) s[j] += (vv[j] != 0) ? 1.0f : 0.0f;
    }
    #pragma unroll
    for (int j = 0; j < 8; ++j) tmp[ts*256 + eg*8 + j] = s[j];
    __syncthreads();
    {
        float p = 0.0f;
        #pragma unroll
        for (int t = 0; t < 8; ++t) p += tmp[t*256 + tid];
        pooled[tid] = p * (1.0f/1024.0f);
    }
    __syncthreads();
    if (tid < NO) {
        float acc = hb[tid];
        for (int c = 0; c < 256; ++c) acc += pooled[c] * hw[tid*256 + c];
        out[b*NO + tid] = acc;
    }
}

// ---------------- launch ----------------
extern "C" void kernel_launch(void* const* d_in, const int* in_sizes, int n_in,
                              void* d_out, int out_size, void* d_ws, size_t ws_size,
                              hipStream_t stream) {
    (void)in_sizes; (void)n_in; (void)out_size; (void)ws_size;
    const float* x       = (const float*)d_in[0];
    const float* conv0_w = (const float*)d_in[1];
    const float* conv0_b = (const float*)d_in[2];
    const float* convs_w = (const float*)d_in[3];
    const float* convs_b = (const float*)d_in[4];
    const float* bn_g    = (const float*)d_in[5];
    const float* bn_b    = (const float*)d_in[6];
    const float* head_w  = (const float*)d_in[7];
    const float* head_b  = (const float*)d_in[8];
    float* out = (float*)d_out;

    char* ws = (char*)d_ws;
    float*          y      = (float*)ws;                              // 67108864 B
    __hip_bfloat16* S      = (__hip_bfloat16*)(ws + 67108864);        // 34603008 B
    __hip_bfloat16* Wfr    = (__hip_bfloat16*)(ws + 101711872);       //  2359296 B
    float*          part   = (float*)(ws + 104071168);                //  1048576 B
    float4*         lifp   = (float4*)(ws + 105119744);               //     4096 B

    prep_w<<<576, 256, 0, stream>>>(convs_w, Wfr);
    conv0_kern<<<dim3(8, 64), 256, 0, stream>>>(x, conv0_w, conv0_b, y, part);
    stats_final<<<256, 64, 0, stream>>>(part, bn_g, bn_b, lifp, 512);
    lif_kern<<<dim3(8, 64), 256, 0, stream>>>(y, lifp, S);

    for (int l = 0; l < 3; ++l) {
        conv_mfma<<<dim3(4, 2, 64), 256, 0, stream>>>(S, Wfr + (size_t)l*393216,
                                                      convs_b + l*256, y, part);
        stats_final<<<256, 64, 0, stream>>>(part, bn_g + (l+1)*256, bn_b + (l+1)*256, lifp, 256);
        lif_kern<<<dim3(8, 64), 256, 0, stream>>>(y, lifp, S);
    }
    head_kern<<<64, 256, 0, stream>>>(S, head_w, head_b, out);
}

// Round 5
// 412.265 us; speedup vs baseline: 1.0560x; 1.0560x over previous
//
#include <hip/hip_runtime.h>
#include <hip/hip_bf16.h>
#include <stdint.h>

#define NB 64
#define NT 1024
#define CIN 8
#define NE 256
#define NO 63
#define TPAD 16
#define TROWS (NT + 2*TPAD)   // 1056
#define LCH 128               // LIF chunk length
#define LWU 48                // LIF warm-up steps (2^-48 decay << fp32 ulp)
#define TT 256                // conv t-tile per block

// lgkm-only barrier: LDS visibility without draining in-flight global loads
#define BAR() asm volatile("s_waitcnt lgkmcnt(0)\n\ts_barrier" ::: "memory")

using bf16x8 = __attribute__((ext_vector_type(8))) short;
using f32x4  = __attribute__((ext_vector_type(4))) float;

// ---- weight split + fragment reorder: convs_w [3][E][E][3] fp32 ->
//      Wfr [l][k][s][e4(16)][cph(8)][lane(64)*8]  bf16, per-lane A-frag order ----
__global__ void prep_w(const float* __restrict__ cw, __hip_bfloat16* __restrict__ wfr) {
    int F = blockIdx.x * 256 + threadIdx.x;          // 576 blocks -> 147456 lanes
    int lane = F & 63;
    int x = F >> 6;
    int cph = x & 7;  x >>= 3;
    int e4  = x & 15; x >>= 4;
    int s   = x & 1;  x >>= 1;
    int k   = x % 3;
    int l   = x / 3;
    int e = e4*16 + (lane & 15);
    int cb = cph*32 + (lane >> 4)*8;
    __hip_bfloat16 outv[8];
    #pragma unroll
    for (int j = 0; j < 8; ++j) {
        float w = cw[((size_t)(l*256 + e)*256 + (cb + j))*3 + k];
        __hip_bfloat16 hi = __float2bfloat16(w);
        if (s == 0) outv[j] = hi;
        else        outv[j] = __float2bfloat16(w - __bfloat162float(hi));
    }
    *(uint4*)(wfr + (size_t)F*8) = *(uint4*)outv;
}

// ---------------- conv0: x [B][T][CIN] -> y [B][T][E] fp32 (+bias) + block stats ----------
__global__ void conv0_kern(const float* __restrict__ x, const float* __restrict__ w0,
                           const float* __restrict__ b0, float* __restrict__ y,
                           float* __restrict__ part) {
    int b = blockIdx.y, tc = blockIdx.x;            // tc: 8 chunks of 128 t
    int e = threadIdx.x;
    int t0 = tc * 128;
    __shared__ float xs[1040];                      // 130 t-rows x 8 c
    for (int i = threadIdx.x; i < 1040; i += 256) {
        int t = t0 - 1 + (i >> 3); int c = i & 7;
        xs[i] = (t >= 0 && t < NT) ? x[((size_t)b*NT + t)*CIN + c] : 0.0f;
    }
    __syncthreads();
    float w[24];
    #pragma unroll
    for (int j = 0; j < 24; ++j) w[j] = w0[e*24 + j];   // [e][c][k]
    float bias = b0[e];
    float s = 0.0f, qq = 0.0f;
    for (int dt = 0; dt < 128; ++dt) {
        float acc = bias;
        #pragma unroll
        for (int c = 0; c < 8; ++c)
            #pragma unroll
            for (int k = 0; k < 3; ++k)
                acc += xs[(dt + k)*8 + c] * w[c*3 + k];
        y[((size_t)b*NT + t0 + dt)*NE + e] = acc;
        s += acc; qq += acc*acc;
    }
    int p = b*8 + tc;
    part[(size_t)p*512 + e]       = s;
    part[(size_t)p*512 + 256 + e] = qq;
}

// ---------------- stats final: reduce np partials per e, wave-parallel ----------------
__global__ void stats_final(const float* __restrict__ part, const float* __restrict__ gamma,
                            const float* __restrict__ beta, float4* __restrict__ lifp, int np) {
    int e = blockIdx.x; int lane = threadIdx.x;
    double s = 0.0, q = 0.0;
    for (int p = lane; p < np; p += 64) {
        s += (double)part[(size_t)p*512 + e];
        q += (double)part[(size_t)p*512 + 256 + e];
    }
    #pragma unroll
    for (int off = 1; off < 64; off <<= 1) {
        s += __shfl_xor(s, off, 64);
        q += __shfl_xor(q, off, 64);
    }
    if (lane == 0) {
        const double N = 65536.0;
        double mean = s / N;
        double var  = q / N - mean*mean;
        float rs = (float)(1.0 / sqrt(var + 1e-5));
        float4 o; o.x = (float)mean; o.y = rs * gamma[e]; o.z = beta[e]; o.w = 0.0f;
        lifp[e] = o;
    }
}

// ---------------- BN apply + chunked LIF scan; WS: write spikes, else pool counts ----------
template<bool WS>
__global__ void lif_kern(const float* __restrict__ y, const float4* __restrict__ lifp,
                         __hip_bfloat16* __restrict__ S, float* __restrict__ pool) {
    int c = blockIdx.x, b = blockIdx.y;
    int e = threadIdx.x;
    float4 pr = lifp[e];
    float mu = pr.x, rsg = pr.y, bet = pr.z;
    const __hip_bfloat16 z   = __float2bfloat16(0.0f);
    const __hip_bfloat16 one = __float2bfloat16(1.0f);
    if (WS) {
        if (c == 0) {       // zero top halo
            for (int r = 0; r < TPAD; ++r) S[((size_t)b*TROWS + r)*NE + e] = z;
        }
        if (c == 7) {       // zero bottom halo
            for (int r = 0; r < TPAD; ++r) S[((size_t)b*TROWS + TPAD + NT + r)*NE + e] = z;
        }
    }
    int t0 = c * LCH;
    int tw = t0 - LWU; if (tw < 0) tw = 0;
    const float* yb = y + (size_t)b*NT*NE + e;
    __hip_bfloat16* sb = S + ((size_t)b*TROWS + TPAD)*NE + e;
    float v = 0.0f;
    #pragma unroll 4
    for (int t = tw; t < t0; ++t) {                 // warm-up, no writes
        float xx = yb[(size_t)t*NE];
        float yn = (xx - mu)*rsg + bet;
        float d  = __fsub_rn(yn, v);
        v = __fadd_rn(v, __fmul_rn(d, 0.5f));
        v = (v >= 1.0f) ? 0.0f : v;
    }
    float cnt = 0.0f;
    #pragma unroll 4
    for (int t = t0; t < t0 + LCH; ++t) {
        float xx = yb[(size_t)t*NE];
        float yn = (xx - mu)*rsg + bet;
        float d  = __fsub_rn(yn, v);
        v = __fadd_rn(v, __fmul_rn(d, 0.5f));       // v + (x - v)/TAU, TAU=2
        bool sp = (v >= 1.0f);
        if (WS) sb[(size_t)t*NE] = sp ? one : z;
        else    cnt += sp ? 1.0f : 0.0f;
        v = sp ? 0.0f : v;
    }
    if (!WS) pool[(size_t)(b*8 + c)*256 + e] = cnt;
}

// ---- main conv v4: R2 structure + lgkm-only barriers + staged reg-prefetch + coalesced stores ----
// block: 128e x 256t, 4 waves; wave (we,wt): 64e x 128t (f=4 e-blocks x g=8 t-blocks of 16x16x32)
__global__ __launch_bounds__(256, 2) void conv_mfma(
    const __hip_bfloat16* __restrict__ Sp,   // [B][TROWS][E] padded spikes
    const __hip_bfloat16* __restrict__ Wfr,  // [k][s][e4][cph][512] frag-ordered, this layer
    const float* __restrict__ bias,
    float* __restrict__ y,                   // [B][T][E]
    float* __restrict__ part)
{
    __shared__ short Bbuf[272*32];           // 272 rows x 32 c (64 B/row, swizzled) = 17408 B
    const int tid  = threadIdx.x;
    const int wave = tid >> 6, lane = tid & 63;
    const int n16  = lane & 15, q = lane >> 4;
    const int we = wave & 1, wt = wave >> 1;
    const int tt = blockIdx.x, et = blockIdx.y, b = blockIdx.z;
    const int t0 = tt * TT;

    f32x4 acc[4][8] = {};
    bf16x8 bfr[8];

    const __hip_bfloat16* Sbase = Sp + ((size_t)b*TROWS + (TPAD - 1 + t0)) * NE;

    // stage regs for ph 0
    uint4 st[5];
    #pragma unroll
    for (int i = 0; i < 5; ++i) {
        int idx = tid + i*256;
        if (idx < 258*4) {
            int r = idx >> 2, sg = idx & 3;
            st[i] = *(const uint4*)(Sbase + (size_t)r*NE + sg*8);
        }
    }

    for (int ph = 0; ph < 8; ++ph) {
        if (ph) BAR();                       // readers of previous ph done (lgkm only)
        #pragma unroll
        for (int i = 0; i < 5; ++i) {
            int idx = tid + i*256;
            if (idx < 258*4) {
                int r = idx >> 2, sg = idx & 3;
                int sgs = sg ^ ((r >> 1) & 3);
                *(uint4*)((char*)Bbuf + r*64 + sgs*16) = st[i];
            }
        }
        BAR();
        if (ph < 7) {                        // prefetch next ph's stage into regs (stays in flight)
            const int c1 = (ph + 1) * 32;
            #pragma unroll
            for (int i = 0; i < 5; ++i) {
                int idx = tid + i*256;
                if (idx < 258*4) {
                    int r = idx >> 2, sg = idx & 3;
                    st[i] = *(const uint4*)(Sbase + (size_t)r*NE + c1 + sg*8);
                }
            }
        }
        #pragma unroll 1
        for (int kk = 0; kk < 3; ++kk) {
            #pragma unroll
            for (int g = 0; g < 8; ++g) {
                int row = wt*128 + g*16 + n16 + kk;
                int sgs = q ^ ((row >> 1) & 3);
                bfr[g] = *(const bf16x8*)((const char*)Bbuf + row*64 + sgs*16);
            }
            #pragma unroll
            for (int s = 0; s < 2; ++s) {
                const __hip_bfloat16* wb = Wfr
                    + ((((size_t)(kk*2 + s)*16 + (et*8 + we*4))*8 + ph) << 9) + lane*8;
                bf16x8 afr[4];
                #pragma unroll
                for (int f = 0; f < 4; ++f)
                    afr[f] = *(const bf16x8*)(wb + ((size_t)f << 12));
                #pragma unroll
                for (int f = 0; f < 4; ++f)
                    #pragma unroll
                    for (int g = 0; g < 8; ++g)
                        acc[f][g] = __builtin_amdgcn_mfma_f32_16x16x32_bf16(afr[f], bfr[g], acc[f][g], 0, 0, 0);
            }
        }
    }

    // epilogue: C col=n16 (t), row=q*4+reg (e); g-outer/f-inner -> consecutive 64B segs fill lines
    float ls[16], lq[16];
    float4 bv[4];
    #pragma unroll
    for (int f = 0; f < 4; ++f) {
        bv[f] = *(const float4*)(bias + et*128 + we*64 + f*16 + q*4);
        ls[f*4+0]=0; ls[f*4+1]=0; ls[f*4+2]=0; ls[f*4+3]=0;
        lq[f*4+0]=0; lq[f*4+1]=0; lq[f*4+2]=0; lq[f*4+3]=0;
    }
    #pragma unroll
    for (int g = 0; g < 8; ++g) {
        int t = t0 + wt*128 + g*16 + n16;
        #pragma unroll
        for (int f = 0; f < 4; ++f) {
            int e_loc = et*128 + we*64 + f*16 + q*4;
            f32x4 a = acc[f][g];
            float4 o;
            o.x = a[0] + bv[f].x; o.y = a[1] + bv[f].y; o.z = a[2] + bv[f].z; o.w = a[3] + bv[f].w;
            *(float4*)(y + ((size_t)b*NT + t)*NE + e_loc) = o;
            ls[f*4+0] += o.x; lq[f*4+0] += o.x*o.x;
            ls[f*4+1] += o.y; lq[f*4+1] += o.y*o.y;
            ls[f*4+2] += o.z; lq[f*4+2] += o.z*o.z;
            ls[f*4+3] += o.w; lq[f*4+3] += o.w*o.w;
        }
    }
    #pragma unroll
    for (int off = 1; off < 16; off <<= 1) {
        #pragma unroll
        for (int i = 0; i < 16; ++i) {
            ls[i] += __shfl_xor(ls[i], off, 64);
            lq[i] += __shfl_xor(lq[i], off, 64);
        }
    }
    BAR();                                   // MFMA LDS reads done everywhere; reuse Bbuf
    float* red = (float*)Bbuf;               // [0..127]=sum, [128..255]=sq
    if (n16 == 0 && wt == 0) {
        #pragma unroll
        for (int f = 0; f < 4; ++f)
            #pragma unroll
            for (int r = 0; r < 4; ++r) {
                int el = we*64 + f*16 + q*4 + r;
                red[el] = ls[f*4+r]; red[128+el] = lq[f*4+r];
            }
    }
    BAR();
    if (n16 == 0 && wt == 1) {
        #pragma unroll
        for (int f = 0; f < 4; ++f)
            #pragma unroll
            for (int r = 0; r < 4; ++r) {
                int el = we*64 + f*16 + q*4 + r;
                red[el] += ls[f*4+r]; red[128+el] += lq[f*4+r];
            }
    }
    BAR();
    if (tid < 128) {
        int p = b*4 + tt;
        part[(size_t)p*512 + et*128 + tid]       = red[tid];
        part[(size_t)p*512 + 256 + et*128 + tid] = red[128 + tid];
    }
}

// ---------------- head final: pooled counts -> [B,E]@[O,E]^T + b ----------------
__global__ void head_final(const float* __restrict__ pool, const float* __restrict__ hw,
                           const float* __restrict__ hb, float* __restrict__ out) {
    int b = blockIdx.x;
    int tid = threadIdx.x;
    __shared__ float pooled[256];
    float s = 0.0f;
    #pragma unroll
    for (int c = 0; c < 8; ++c) s += pool[(size_t)(b*8 + c)*256 + tid];
    pooled[tid] = s * (1.0f/1024.0f);        // exact: integer count / 2^10
    __syncthreads();
    if (tid < NO) {
        float acc = hb[tid];
        for (int c = 0; c < 256; ++c) acc += pooled[c] * hw[tid*256 + c];
        out[b*NO + tid] = acc;
    }
}

// ---------------- launch ----------------
extern "C" void kernel_launch(void* const* d_in, const int* in_sizes, int n_in,
                              void* d_out, int out_size, void* d_ws, size_t ws_size,
                              hipStream_t stream) {
    (void)in_sizes; (void)n_in; (void)out_size; (void)ws_size;
    const float* x       = (const float*)d_in[0];
    const float* conv0_w = (const float*)d_in[1];
    const float* conv0_b = (const float*)d_in[2];
    const float* convs_w = (const float*)d_in[3];
    const float* convs_b = (const float*)d_in[4];
    const float* bn_g    = (const float*)d_in[5];
    const float* bn_b    = (const float*)d_in[6];
    const float* head_w  = (const float*)d_in[7];
    const float* head_b  = (const float*)d_in[8];
    float* out = (float*)d_out;

    char* ws = (char*)d_ws;
    float*          y      = (float*)ws;                              // 67108864 B
    __hip_bfloat16* S      = (__hip_bfloat16*)(ws + 67108864);        // 34603008 B
    __hip_bfloat16* Wfr    = (__hip_bfloat16*)(ws + 101711872);       //  2359296 B
    float*          part   = (float*)(ws + 104071168);                //  1048576 B
    float4*         lifp   = (float4*)(ws + 105119744);               //     4096 B
    float*          pool   = part + 131072;                           // 2nd half of part buffer

    prep_w<<<576, 256, 0, stream>>>(convs_w, Wfr);
    conv0_kern<<<dim3(8, 64), 256, 0, stream>>>(x, conv0_w, conv0_b, y, part);
    stats_final<<<256, 64, 0, stream>>>(part, bn_g, bn_b, lifp, 512);
    lif_kern<true><<<dim3(8, 64), 256, 0, stream>>>(y, lifp, S, nullptr);

    for (int l = 0; l < 3; ++l) {
        conv_mfma<<<dim3(4, 2, 64), 256, 0, stream>>>(S, Wfr + (size_t)l*393216,
                                                      convs_b + l*256, y, part);
        stats_final<<<256, 64, 0, stream>>>(part, bn_g + (l+1)*256, bn_b + (l+1)*256, lifp, 256);
        if (l < 2) lif_kern<true ><<<dim3(8, 64), 256, 0, stream>>>(y, lifp, S, nullptr);
        else       lif_kern<false><<<dim3(8, 64), 256, 0, stream>>>(y, lifp, S, pool);
    }
    head_final<<<64, 256, 0, stream>>>(pool, head_w, head_b, out);
}

// Round 6
// 383.601 us; speedup vs baseline: 1.1349x; 1.0747x over previous
//
#include <hip/hip_runtime.h>
#include <hip/hip_bf16.h>
#include <stdint.h>

#define NB 64
#define NT 1024
#define CIN 8
#define NE 256
#define NO 63
#define TPAD 16
#define TROWS (NT + 2*TPAD)   // 1056
#define LCH 128               // LIF chunk length
#define LWU 48                // LIF warm-up steps (2^-48 decay << fp32 ulp)
#define TT 256                // conv t-tile per block

using bf16x8 = __attribute__((ext_vector_type(8))) short;
using f32x4  = __attribute__((ext_vector_type(4))) float;

// ---- weight split + fragment reorder: convs_w [3][E][E][3] fp32 ->
//      Wfr [l][k][s][e4(16)][cph(8)][lane(64)*8]  bf16, per-lane A-frag order ----
__global__ void prep_w(const float* __restrict__ cw, __hip_bfloat16* __restrict__ wfr) {
    int F = blockIdx.x * 256 + threadIdx.x;          // 576 blocks -> 147456 lanes
    int lane = F & 63;
    int x = F >> 6;
    int cph = x & 7;  x >>= 3;
    int e4  = x & 15; x >>= 4;
    int s   = x & 1;  x >>= 1;
    int k   = x % 3;
    int l   = x / 3;
    int e = e4*16 + (lane & 15);
    int cb = cph*32 + (lane >> 4)*8;
    __hip_bfloat16 outv[8];
    #pragma unroll
    for (int j = 0; j < 8; ++j) {
        float w = cw[((size_t)(l*256 + e)*256 + (cb + j))*3 + k];
        __hip_bfloat16 hi = __float2bfloat16(w);
        if (s == 0) outv[j] = hi;
        else        outv[j] = __float2bfloat16(w - __bfloat162float(hi));
    }
    *(uint4*)(wfr + (size_t)F*8) = *(uint4*)outv;
}

// ---------------- conv0: x [B][T][CIN] -> y [B][T][E] fp32 (+bias) + block stats ----------
__global__ void conv0_kern(const float* __restrict__ x, const float* __restrict__ w0,
                           const float* __restrict__ b0, float* __restrict__ y,
                           float* __restrict__ part) {
    int b = blockIdx.y, tc = blockIdx.x;            // tc: 8 chunks of 128 t
    int e = threadIdx.x;
    int t0 = tc * 128;
    __shared__ float xs[1040];                      // 130 t-rows x 8 c
    for (int i = threadIdx.x; i < 1040; i += 256) {
        int t = t0 - 1 + (i >> 3); int c = i & 7;
        xs[i] = (t >= 0 && t < NT) ? x[((size_t)b*NT + t)*CIN + c] : 0.0f;
    }
    __syncthreads();
    float w[24];
    #pragma unroll
    for (int j = 0; j < 24; ++j) w[j] = w0[e*24 + j];   // [e][c][k]
    float bias = b0[e];
    float s = 0.0f, qq = 0.0f;
    for (int dt = 0; dt < 128; ++dt) {
        float acc = bias;
        #pragma unroll
        for (int c = 0; c < 8; ++c)
            #pragma unroll
            for (int k = 0; k < 3; ++k)
                acc += xs[(dt + k)*8 + c] * w[c*3 + k];
        y[((size_t)b*NT + t0 + dt)*NE + e] = acc;
        s += acc; qq += acc*acc;
    }
    int p = b*8 + tc;
    part[(size_t)p*512 + e]       = s;
    part[(size_t)p*512 + 256 + e] = qq;
}

// ---------------- stats final: reduce np partials per e, wave-parallel ----------------
__global__ void stats_final(const float* __restrict__ part, const float* __restrict__ gamma,
                            const float* __restrict__ beta, float4* __restrict__ lifp, int np) {
    int e = blockIdx.x; int lane = threadIdx.x;
    double s = 0.0, q = 0.0;
    for (int p = lane; p < np; p += 64) {
        s += (double)part[(size_t)p*512 + e];
        q += (double)part[(size_t)p*512 + 256 + e];
    }
    #pragma unroll
    for (int off = 1; off < 64; off <<= 1) {
        s += __shfl_xor(s, off, 64);
        q += __shfl_xor(q, off, 64);
    }
    if (lane == 0) {
        const double N = 65536.0;
        double mean = s / N;
        double var  = q / N - mean*mean;
        float rs = (float)(1.0 / sqrt(var + 1e-5));
        float4 o; o.x = (float)mean; o.y = rs * gamma[e]; o.z = beta[e]; o.w = 0.0f;
        lifp[e] = o;
    }
}

// ---------------- BN apply + chunked LIF scan; WS: write spikes, else pool counts ----------
template<bool WS>
__global__ void lif_kern(const float* __restrict__ y, const float4* __restrict__ lifp,
                         __hip_bfloat16* __restrict__ S, float* __restrict__ pool) {
    int c = blockIdx.x, b = blockIdx.y;
    int e = threadIdx.x;
    float4 pr = lifp[e];
    float mu = pr.x, rsg = pr.y, bet = pr.z;
    const __hip_bfloat16 z   = __float2bfloat16(0.0f);
    const __hip_bfloat16 one = __float2bfloat16(1.0f);
    if (WS) {
        if (c == 0) {       // zero top halo
            for (int r = 0; r < TPAD; ++r) S[((size_t)b*TROWS + r)*NE + e] = z;
        }
        if (c == 7) {       // zero bottom halo
            for (int r = 0; r < TPAD; ++r) S[((size_t)b*TROWS + TPAD + NT + r)*NE + e] = z;
        }
    }
    int t0 = c * LCH;
    int tw = t0 - LWU; if (tw < 0) tw = 0;
    const float* yb = y + (size_t)b*NT*NE + e;
    __hip_bfloat16* sb = S + ((size_t)b*TROWS + TPAD)*NE + e;
    float v = 0.0f;
    #pragma unroll 4
    for (int t = tw; t < t0; ++t) {                 // warm-up, no writes
        float xx = yb[(size_t)t*NE];
        float yn = (xx - mu)*rsg + bet;
        float d  = __fsub_rn(yn, v);
        v = __fadd_rn(v, __fmul_rn(d, 0.5f));
        v = (v >= 1.0f) ? 0.0f : v;
    }
    float cnt = 0.0f;
    #pragma unroll 4
    for (int t = t0; t < t0 + LCH; ++t) {
        float xx = yb[(size_t)t*NE];
        float yn = (xx - mu)*rsg + bet;
        float d  = __fsub_rn(yn, v);
        v = __fadd_rn(v, __fmul_rn(d, 0.5f));       // v + (x - v)/TAU, TAU=2
        bool sp = (v >= 1.0f);
        if (WS) sb[(size_t)t*NE] = sp ? one : z;
        else    cnt += sp ? 1.0f : 0.0f;
        v = sp ? 0.0f : v;
    }
    if (!WS) pool[(size_t)(b*8 + c)*256 + e] = cnt;
}

// ---- main conv v5: R2 structure, 4 phases of 64 c (8 barriers/block) ----
// block: 128e x 256t, 4 waves; wave (we,wt): 64e x 128t (f=4 e-blocks x g=8 t-blocks of 16x16x32)
#define SROWS 258               // staged B rows per phase (256 t + 2 halo)

__global__ __launch_bounds__(256, 2) void conv_mfma(
    const __hip_bfloat16* __restrict__ Sp,   // [B][TROWS][E] padded spikes
    const __hip_bfloat16* __restrict__ Wfr,  // [k][s][e4][cph][512] frag-ordered, this layer
    const float* __restrict__ bias,
    float* __restrict__ y,                   // [B][T][E]
    float* __restrict__ part)
{
    __shared__ short Bbuf[SROWS*64];         // 258 rows x 64 c (128 B/row, seg-swizzled) = 33024 B
    const int tid  = threadIdx.x;
    const int wave = tid >> 6, lane = tid & 63;
    const int n16  = lane & 15, q = lane >> 4;
    const int we = wave & 1, wt = wave >> 1;
    const int tt = blockIdx.x, et = blockIdx.y, b = blockIdx.z;
    const int t0 = tt * TT;

    f32x4 acc[4][8] = {};
    bf16x8 bfr[8];

    const __hip_bfloat16* Sbase = Sp + ((size_t)b*TROWS + (TPAD - 1 + t0)) * NE;

    for (int ph = 0; ph < 4; ++ph) {
        const int c0 = ph * 64;
        __syncthreads();
        // stage B tile: 258 rows x 64 c; 16B segs swizzled by (row & 7)
        for (int idx = tid; idx < SROWS*8; idx += 256) {
            int r = idx >> 3, sg = idx & 7;
            uint4 d = *(const uint4*)(Sbase + (size_t)r*NE + c0 + sg*8);
            int sgs = sg ^ (r & 7);
            *(uint4*)((char*)Bbuf + r*128 + sgs*16) = d;
        }
        __syncthreads();
        #pragma unroll 1
        for (int kk = 0; kk < 3; ++kk) {
            #pragma unroll
            for (int cc = 0; cc < 2; ++cc) {
                #pragma unroll
                for (int g = 0; g < 8; ++g) {
                    int row = wt*128 + g*16 + n16 + kk;
                    int sgs = (cc*4 + q) ^ (row & 7);
                    bfr[g] = *(const bf16x8*)((const char*)Bbuf + row*128 + sgs*16);
                }
                #pragma unroll
                for (int s = 0; s < 2; ++s) {
                    const __hip_bfloat16* wb = Wfr
                        + ((((size_t)(kk*2 + s)*16 + (et*8 + we*4))*8 + (ph*2 + cc)) << 9) + lane*8;
                    bf16x8 afr[4];
                    #pragma unroll
                    for (int f = 0; f < 4; ++f)
                        afr[f] = *(const bf16x8*)(wb + ((size_t)f << 12));
                    #pragma unroll
                    for (int f = 0; f < 4; ++f)
                        #pragma unroll
                        for (int g = 0; g < 8; ++g)
                            acc[f][g] = __builtin_amdgcn_mfma_f32_16x16x32_bf16(afr[f], bfr[g], acc[f][g], 0, 0, 0);
                }
            }
        }
    }

    // epilogue: C col=n16 (t), row=q*4+reg (e); store y + per-e block stats (R2 order)
    float ls[16], lq[16];
    #pragma unroll
    for (int f = 0; f < 4; ++f) {
        int e_loc = et*128 + we*64 + f*16 + q*4;
        float4 bv = *(const float4*)(bias + e_loc);
        float s0=0,s1=0,s2=0,s3=0, q0=0,q1=0,q2=0,q3=0;
        #pragma unroll
        for (int g = 0; g < 8; ++g) {
            int t = t0 + wt*128 + g*16 + n16;
            f32x4 a = acc[f][g];
            float4 o;
            o.x = a[0] + bv.x; o.y = a[1] + bv.y; o.z = a[2] + bv.z; o.w = a[3] + bv.w;
            *(float4*)(y + ((size_t)b*NT + t)*NE + e_loc) = o;
            s0 += o.x; q0 += o.x*o.x;
            s1 += o.y; q1 += o.y*o.y;
            s2 += o.z; q2 += o.z*o.z;
            s3 += o.w; q3 += o.w*o.w;
        }
        ls[f*4+0]=s0; lq[f*4+0]=q0;
        ls[f*4+1]=s1; lq[f*4+1]=q1;
        ls[f*4+2]=s2; lq[f*4+2]=q2;
        ls[f*4+3]=s3; lq[f*4+3]=q3;
    }
    #pragma unroll
    for (int off = 1; off < 16; off <<= 1) {
        #pragma unroll
        for (int i = 0; i < 16; ++i) {
            ls[i] += __shfl_xor(ls[i], off, 64);
            lq[i] += __shfl_xor(lq[i], off, 64);
        }
    }
    __syncthreads();
    float* red = (float*)Bbuf;                  // reuse LDS: [0..127]=sum, [128..255]=sq
    if (n16 == 0 && wt == 0) {
        #pragma unroll
        for (int f = 0; f < 4; ++f)
            #pragma unroll
            for (int r = 0; r < 4; ++r) {
                int el = we*64 + f*16 + q*4 + r;
                red[el] = ls[f*4+r]; red[128+el] = lq[f*4+r];
            }
    }
    __syncthreads();
    if (n16 == 0 && wt == 1) {
        #pragma unroll
        for (int f = 0; f < 4; ++f)
            #pragma unroll
            for (int r = 0; r < 4; ++r) {
                int el = we*64 + f*16 + q*4 + r;
                red[el] += ls[f*4+r]; red[128+el] += lq[f*4+r];
            }
    }
    __syncthreads();
    if (tid < 128) {
        int p = b*4 + tt;
        part[(size_t)p*512 + et*128 + tid]       = red[tid];
        part[(size_t)p*512 + 256 + et*128 + tid] = red[128 + tid];
    }
}

// ---------------- head final: pooled counts -> [B,E]@[O,E]^T + b ----------------
__global__ void head_final(const float* __restrict__ pool, const float* __restrict__ hw,
                           const float* __restrict__ hb, float* __restrict__ out) {
    int b = blockIdx.x;
    int tid = threadIdx.x;
    __shared__ float pooled[256];
    float s = 0.0f;
    #pragma unroll
    for (int c = 0; c < 8; ++c) s += pool[(size_t)(b*8 + c)*256 + tid];
    pooled[tid] = s * (1.0f/1024.0f);        // exact: integer count / 2^10
    __syncthreads();
    if (tid < NO) {
        float acc = hb[tid];
        for (int c = 0; c < 256; ++c) acc += pooled[c] * hw[tid*256 + c];
        out[b*NO + tid] = acc;
    }
}

// ---------------- launch ----------------
extern "C" void kernel_launch(void* const* d_in, const int* in_sizes, int n_in,
                              void* d_out, int out_size, void* d_ws, size_t ws_size,
                              hipStream_t stream) {
    (void)in_sizes; (void)n_in; (void)out_size; (void)ws_size;
    const float* x       = (const float*)d_in[0];
    const float* conv0_w = (const float*)d_in[1];
    const float* conv0_b = (const float*)d_in[2];
    const float* convs_w = (const float*)d_in[3];
    const float* convs_b = (const float*)d_in[4];
    const float* bn_g    = (const float*)d_in[5];
    const float* bn_b    = (const float*)d_in[6];
    const float* head_w  = (const float*)d_in[7];
    const float* head_b  = (const float*)d_in[8];
    float* out = (float*)d_out;

    char* ws = (char*)d_ws;
    float*          y      = (float*)ws;                              // 67108864 B
    __hip_bfloat16* S      = (__hip_bfloat16*)(ws + 67108864);        // 34603008 B
    __hip_bfloat16* Wfr    = (__hip_bfloat16*)(ws + 101711872);       //  2359296 B
    float*          part   = (float*)(ws + 104071168);                //  1048576 B
    float4*         lifp   = (float4*)(ws + 105119744);               //     4096 B
    float*          pool   = part + 131072;                           // 2nd half of part buffer

    prep_w<<<576, 256, 0, stream>>>(convs_w, Wfr);
    conv0_kern<<<dim3(8, 64), 256, 0, stream>>>(x, conv0_w, conv0_b, y, part);
    stats_final<<<256, 64, 0, stream>>>(part, bn_g, bn_b, lifp, 512);
    lif_kern<true><<<dim3(8, 64), 256, 0, stream>>>(y, lifp, S, nullptr);

    for (int l = 0; l < 3; ++l) {
        conv_mfma<<<dim3(4, 2, 64), 256, 0, stream>>>(S, Wfr + (size_t)l*393216,
                                                      convs_b + l*256, y, part);
        stats_final<<<256, 64, 0, stream>>>(part, bn_g + (l+1)*256, bn_b + (l+1)*256, lifp, 256);
        if (l < 2) lif_kern<true ><<<dim3(8, 64), 256, 0, stream>>>(y, lifp, S, nullptr);
        else       lif_kern<false><<<dim3(8, 64), 256, 0, stream>>>(y, lifp, S, pool);
    }
    head_final<<<64, 256, 0, stream>>>(pool, head_w, head_b, out);
}